// Round 1
// baseline (360.691 us; speedup 1.0000x reference)
//
#include <hip/hip_runtime.h>
#include <math.h>

// Problem constants (from reference): x [64,4096,64] fp32, embedding [512,64] fp32
#define N_ROWS   262144   // 64*4096
#define DIM      64
#define KCODES   512
#define MT       64       // rows per block
#define NTHREADS 256
#define ESTRIDE  516      // padded LDS stride for codebook chunk [16][516]

// ws layout:
//   [0,    2048)  float esq[512]
//   [2048, 4096)  int   counts[512]
//   [4096, 4100)  float loss accumulator

__global__ __launch_bounds__(512) void vq_prep(const float* __restrict__ emb,
                                               float* __restrict__ esq,
                                               int* __restrict__ counts,
                                               float* __restrict__ lossp) {
    int k = threadIdx.x;                       // 512 threads, 1 block
    const float* e = emb + (size_t)k * DIM;
    float s = 0.f;
    #pragma unroll
    for (int d = 0; d < DIM; ++d) s += e[d] * e[d];
    esq[k] = s;
    counts[k] = 0;
    if (k == 0) *lossp = 0.f;
}

__global__ __launch_bounds__(NTHREADS, 2) void vq_main(
    const float* __restrict__ x, const float* __restrict__ emb,
    const float* __restrict__ g_esq, int* __restrict__ g_counts,
    float* __restrict__ g_loss, float* __restrict__ out)
{
    __shared__ float xs_t[DIM * MT];                 // x tile transposed [d][r], 16 KB
    __shared__ float esq_s[KCODES];                  // 2 KB
    __shared__ int   idx_s[MT];
    __shared__ float wred[4];
    // codebook chunk [16][ESTRIDE] (33 KB); reused as argmin reduction space after loop
    __shared__ __align__(16) char dynbuf[16 * ESTRIDE * 4];
    float* es_t = (float*)dynbuf;
    float* redv = (float*)dynbuf;                    // [MT][32] float
    int*   redi = (int*)(dynbuf + MT * 32 * sizeof(float)); // [MT][32] int

    const int tid = threadIdx.x;
    const int cg  = tid & 31;      // col group (32): cols 4*cg + 128*j + q
    const int rg  = tid >> 5;      // row group (8):  rows rg*8 .. rg*8+7
    const int r0  = rg * 8;
    const int R0  = blockIdx.x * MT;

    // ---- stage x tile transposed (coalesced float4 reads) ----
    #pragma unroll
    for (int i = 0; i < 4; ++i) {
        int fid = tid + NTHREADS * i;    // 0..1023 (64 rows * 16 float4)
        int r = fid >> 4;
        int q = fid & 15;
        float4 v = *(const float4*)&x[(size_t)(R0 + r) * DIM + 4 * q];
        xs_t[(4*q+0)*MT + r] = v.x;
        xs_t[(4*q+1)*MT + r] = v.y;
        xs_t[(4*q+2)*MT + r] = v.z;
        xs_t[(4*q+3)*MT + r] = v.w;
    }
    esq_s[tid]       = g_esq[tid];
    esq_s[tid + 256] = g_esq[tid + 256];

    float4 acc[8][4];                               // 8 rows x 16 cols
    #pragma unroll
    for (int i = 0; i < 8; ++i)
        #pragma unroll
        for (int j = 0; j < 4; ++j) acc[i][j] = make_float4(0.f, 0.f, 0.f, 0.f);

    // ---- main loop: 4 chunks of 16 d's ----
    for (int ch = 0; ch < 4; ++ch) {
        __syncthreads();                             // protect es_t before overwrite
        const int dc = ch * 16;
        #pragma unroll
        for (int i = 0; i < 8; ++i) {                // stage codebook chunk [512][16] -> [16][516]
            int fid = tid + NTHREADS * i;            // 0..2047
            int k = fid >> 2;
            int q = fid & 3;
            float4 v = *(const float4*)&emb[(size_t)k * DIM + dc + 4 * q];
            es_t[(4*q+0)*ESTRIDE + k] = v.x;
            es_t[(4*q+1)*ESTRIDE + k] = v.y;
            es_t[(4*q+2)*ESTRIDE + k] = v.z;
            es_t[(4*q+3)*ESTRIDE + k] = v.w;
        }
        __syncthreads();
        #pragma unroll 4
        for (int dl = 0; dl < 16; ++dl) {
            const int d = dc + dl;
            float4 a0 = *(const float4*)&xs_t[d * MT + r0];       // broadcast reads
            float4 a1 = *(const float4*)&xs_t[d * MT + r0 + 4];
            float4 b0 = *(const float4*)&es_t[dl * ESTRIDE + 4*cg];        // contiguous across lanes
            float4 b1 = *(const float4*)&es_t[dl * ESTRIDE + 4*cg + 128];
            float4 b2 = *(const float4*)&es_t[dl * ESTRIDE + 4*cg + 256];
            float4 b3 = *(const float4*)&es_t[dl * ESTRIDE + 4*cg + 384];
            float  a[8]  = {a0.x,a0.y,a0.z,a0.w,a1.x,a1.y,a1.z,a1.w};
            float4 b[4]  = {b0,b1,b2,b3};
            #pragma unroll
            for (int i = 0; i < 8; ++i)
                #pragma unroll
                for (int j = 0; j < 4; ++j) {
                    acc[i][j].x += a[i] * b[j].x;
                    acc[i][j].y += a[i] * b[j].y;
                    acc[i][j].z += a[i] * b[j].z;
                    acc[i][j].w += a[i] * b[j].w;
                }
        }
    }
    __syncthreads();   // all es_t reads done; dynbuf becomes reduction space

    // ---- per-thread argmin per row (dist = ||e||^2 - 2*dot; ||x||^2 constant per row) ----
    float bv[8]; int bi[8];
    #pragma unroll
    for (int i = 0; i < 8; ++i) { bv[i] = 3.4e38f; bi[i] = 0; }
    #pragma unroll
    for (int j = 0; j < 4; ++j) {
        #pragma unroll
        for (int q = 0; q < 4; ++q) {                // ascending col order within thread
            int col = 128*j + 4*cg + q;
            float e2 = esq_s[col];
            #pragma unroll
            for (int i = 0; i < 8; ++i) {
                float s = (q==0) ? acc[i][j].x : (q==1) ? acc[i][j].y
                        : (q==2) ? acc[i][j].z : acc[i][j].w;
                float dist = e2 - 2.f * s;
                if (dist < bv[i]) { bv[i] = dist; bi[i] = col; }   // strict <: first min wins
            }
        }
    }
    #pragma unroll
    for (int i = 0; i < 8; ++i) {
        redv[(r0 + i) * 32 + cg] = bv[i];
        redi[(r0 + i) * 32 + cg] = bi[i];
    }
    __syncthreads();
    if (tid < MT) {
        float best = redv[tid * 32];
        int   bidx = redi[tid * 32];
        #pragma unroll
        for (int c = 1; c < 32; ++c) {
            float v  = redv[tid * 32 + c];
            int   ix = redi[tid * 32 + c];
            if (v < best || (v == best && ix < bidx)) { best = v; bidx = ix; }
        }
        idx_s[tid] = bidx;
    }
    __syncthreads();

    // ---- gather code row, write q_st = x + (e - x) (reference fp32 op order), loss ----
    const int r  = tid >> 2;
    const int d0 = (tid & 3) * 16;
    const int ki = idx_s[r];
    const float* erow = emb + (size_t)ki * DIM;
    float lpart = 0.f;
    #pragma unroll
    for (int s4 = 0; s4 < 4; ++s4) {
        int d = d0 + 4 * s4;
        float4 e4 = *(const float4*)&erow[d];
        float xv0 = xs_t[(d+0)*MT + r];
        float xv1 = xs_t[(d+1)*MT + r];
        float xv2 = xs_t[(d+2)*MT + r];
        float xv3 = xs_t[(d+3)*MT + r];
        float f0 = e4.x - xv0, f1 = e4.y - xv1, f2 = e4.z - xv2, f3 = e4.w - xv3;
        float4 o;
        o.x = xv0 + f0; o.y = xv1 + f1; o.z = xv2 + f2; o.w = xv3 + f3;
        *(float4*)&out[(size_t)(R0 + r) * DIM + d] = o;
        lpart += f0*f0 + f1*f1 + f2*f2 + f3*f3;
    }
    // block-reduce loss partial
    #pragma unroll
    for (int off = 32; off > 0; off >>= 1) lpart += __shfl_down(lpart, off);
    if ((tid & 63) == 0) wred[tid >> 6] = lpart;
    __syncthreads();
    if (tid == 0) atomicAdd(g_loss, wred[0] + wred[1] + wred[2] + wred[3]);
    if (tid < MT) atomicAdd(&g_counts[idx_s[tid]], 1);
}

__global__ __launch_bounds__(512) void vq_final(const int* __restrict__ counts,
                                                const float* __restrict__ lossp,
                                                float* __restrict__ out) {
    __shared__ float red[8];
    int k = threadIdx.x;                              // 512 threads, 1 block
    float p = (float)counts[k] * (1.f / 262144.f);
    float t = p * logf(p + 1e-10f);
    #pragma unroll
    for (int off = 32; off > 0; off >>= 1) t += __shfl_down(t, off);
    if ((k & 63) == 0) red[k >> 6] = t;
    __syncthreads();
    if (k == 0) {
        float s = 0.f;
        #pragma unroll
        for (int i = 0; i < 8; ++i) s += red[i];
        out[16777216] = (*lossp) * (0.25f / 16777216.f);  // COMMITMENT_COST * mean
        out[16777217] = expf(-s);                          // perplexity
    }
}

extern "C" void kernel_launch(void* const* d_in, const int* in_sizes, int n_in,
                              void* d_out, int out_size, void* d_ws, size_t ws_size,
                              hipStream_t stream) {
    const float* x   = (const float*)d_in[0];
    const float* emb = (const float*)d_in[1];
    float* out    = (float*)d_out;
    float* esq    = (float*)d_ws;
    int*   counts = (int*)((char*)d_ws + 2048);
    float* lossp  = (float*)((char*)d_ws + 4096);

    vq_prep<<<1, 512, 0, stream>>>(emb, esq, counts, lossp);
    vq_main<<<N_ROWS / MT, NTHREADS, 0, stream>>>(x, emb, esq, counts, lossp, out);
    vq_final<<<1, 512, 0, stream>>>(counts, lossp, out);
}